// Round 4
// baseline (714.001 us; speedup 1.0000x reference)
//
#include <hip/hip_runtime.h>
#include <hip/hip_bf16.h>
#include <stdint.h>

#define LL 512
#define BB 64
#define CC 512
#define TM 255   // meeting point: fwd covers emits 0..255, bwd covers 256..511

typedef float float4v __attribute__((ext_vector_type(4)));
typedef int   int4v   __attribute__((ext_vector_type(4)));
typedef int   int8v   __attribute__((ext_vector_type(8)));

// ws layout (bytes)
#define WS_SPART  524288   // 32 f32 score partials
#define WS_SVA    524416   // 64 f32
#define WS_SVB    524672   // 64 f32
#define WS_ALPHA  528384   // 64*512 f32 (class-ordered)
#define WS_BETA   659456   // 64*512 f32 (class-ordered)

// position permutation shared by p8 rows and E/E^T columns:
//   kperm(P) = 64*(P>>6) + 16*(P&3) + ((P>>2)&15)
//
// normalization (pow2): stored S_t = quant(v_t * 2^-g_t), v_t = MFMA(S_{t-1})*ex_t,
//   g_t = floor(log2(M'_{t-1})) + 6,  M'_{t-1} = max(stored S_{t-1})  (ring slot, 1-step lag)
//   true alpha_t = S_t * D_t, logD = gsum * ln2  (exact)

__device__ __forceinline__ int kperm(int p) {
    return 64 * (p >> 6) + 16 * (p & 3) + ((p >> 2) & 15);
}

__device__ __forceinline__ bool mask_at(const void* maskp, bool is_byte, int t, int b) {
    if (is_byte) return ((const unsigned char*)maskp)[t * BB + b] != 0;
    return ((const int*)maskp)[t * BB + b] != 0;
}

__device__ __forceinline__ float rowmax16_dpp(float x) {
    int t;
    t = __builtin_amdgcn_update_dpp(0, __float_as_int(x), 0x128, 0xF, 0xF, true); // ror:8
    x = fmaxf(x, __int_as_float(t));
    t = __builtin_amdgcn_update_dpp(0, __float_as_int(x), 0x124, 0xF, 0xF, true); // ror:4
    x = fmaxf(x, __int_as_float(t));
    t = __builtin_amdgcn_update_dpp(0, __float_as_int(x), 0x122, 0xF, 0xF, true); // ror:2
    x = fmaxf(x, __int_as_float(t));
    t = __builtin_amdgcn_update_dpp(0, __float_as_int(x), 0x121, 0xF, 0xF, true); // ror:1
    x = fmaxf(x, __int_as_float(t));
    return x;
}

// LDS-exchange barrier WITHOUT vmcnt drain: global prefetches stay in flight.
__device__ __forceinline__ void step_barrier() {
    asm volatile("s_waitcnt lgkmcnt(0)" ::: "memory");
    __builtin_amdgcn_sched_barrier(0);
    __builtin_amdgcn_s_barrier();
    asm volatile("" ::: "memory");
}

// blocks 0..3: fwd alpha t=1..255 (len>=256 -> unguarded)
// blocks 4..7: bwd beta t=510..255 (freeze-until-birth, branchless)
// blocks 8..39: score (per-block partials, no atomics)
__launch_bounds__(512, 2)
__global__ void crf_scan_kernel(const float* __restrict__ emit,
                                const int* __restrict__ target,
                                const void* __restrict__ maskp,
                                const float* __restrict__ trans,
                                const float* __restrict__ tfs,
                                const float* __restrict__ t2e,
                                unsigned char* __restrict__ ws) {
    const int tid = threadIdx.x;
    const bool is_byte = ((const unsigned char*)maskp)[1] != 0;

    if (blockIdx.x >= 8) {   // -------- score part --------
        __shared__ float sred[8];
        int sb = blockIdx.x - 8;
        float val = 0.0f;
        for (int e = sb * 512 + tid; e < LL * BB; e += 32 * 512) {
            int t = e >> 6, b = e & 63;
            if (mask_at(maskp, is_byte, t, b)) {
                int tg  = target[t * BB + b];
                float v = emit[(size_t)(t * BB + b) * CC + tg];
                if (t > 0) v += trans[(size_t)target[(t - 1) * BB + b] * CC + tg];
                val += v;
            }
        }
        if (sb == 0 && tid < BB) {
            int b = tid;
            val += tfs[target[b]];
            int lo = 0, hi = LL;
            while (lo < hi) {
                int mid = (lo + hi) >> 1;
                if (mask_at(maskp, is_byte, mid, b)) lo = mid + 1; else hi = mid;
            }
            val += t2e[target[(lo - 1) * BB + b]];
        }
        for (int off = 32; off > 0; off >>= 1) val += __shfl_down(val, off);
        if ((tid & 63) == 0) sred[tid >> 6] = val;
        __syncthreads();
        if (tid == 0) {
            float s = 0.0f;
            for (int i = 0; i < 8; ++i) s += sred[i];
            ((float*)(ws + WS_SPART))[sb] = s;
        }
        return;
    }

    const bool is_fwd = blockIdx.x < 4;
    const int B0 = (is_fwd ? blockIdx.x : blockIdx.x - 4) * 16;

    __shared__ __align__(16) unsigned char p8[2][16 * 528];
    __shared__ __align__(16) float mslot[4][16];   // rowmax ring (stored-scale M')
    __shared__ float m0S[16];
    __shared__ float red[16][32];
    __shared__ int   lenS[16];
    __shared__ float mInitS;

    const int wv   = tid >> 6;
    const int lane = tid & 63;
    const int q    = lane >> 4;
    const int r15  = lane & 15;

    // ---- build E (fwd) / E^T (bwd) MFMA B-fragments directly from trans (once) ----
    int8v ef[4][4];
#pragma unroll
    for (int nt = 0; nt < 4; ++nt) {
        int n = (wv * 4 + nt) * 16 + r15;
#pragma unroll
        for (int kk4 = 0; kk4 < 4; ++kk4) {
            int pb = kk4 * 128 + q * 32;
            int8v v;
#pragma unroll
            for (int d = 0; d < 8; ++d) {
                int p0 = pb + (d & 3) * 4 + (d >> 2) * 16;
                int kb = 64 * (p0 >> 6) + ((p0 >> 2) & 15);
                float f0, f1, f2, f3;
                if (is_fwd) {
                    f0 = __expf(trans[(size_t)(kb +  0) * CC + n]);
                    f1 = __expf(trans[(size_t)(kb + 16) * CC + n]);
                    f2 = __expf(trans[(size_t)(kb + 32) * CC + n]);
                    f3 = __expf(trans[(size_t)(kb + 48) * CC + n]);
                } else {
                    f0 = __expf(trans[(size_t)n * CC + kb +  0]);
                    f1 = __expf(trans[(size_t)n * CC + kb + 16]);
                    f2 = __expf(trans[(size_t)n * CC + kb + 32]);
                    f3 = __expf(trans[(size_t)n * CC + kb + 48]);
                }
                int r = 0;
                r = __builtin_amdgcn_cvt_pk_fp8_f32(f0, f1, r, false);
                r = __builtin_amdgcn_cvt_pk_fp8_f32(f2, f3, r, true);
                v[d] = r;
            }
            ef[nt][kk4] = v;
        }
    }

    const int c5 = tid >> 5;
    const int s5 = tid & 31;

    if (is_fwd) {
        // ---- fwd init pass 1: m0 = max(emit[0]+tfs) per chain ----
        {
            float lmax = -3.0e38f;
#pragma unroll
            for (int i = 0; i < 4; ++i) {
                int j4 = s5 + 32 * i;
                float4v em = *(const float4v*)(emit + (size_t)(B0 + c5) * CC + 4 * j4);
                float4v tf = *(const float4v*)(tfs + 4 * j4);
                float4v a = em + tf;
                lmax = fmaxf(lmax, fmaxf(fmaxf(a.x, a.y), fmaxf(a.z, a.w)));
            }
            red[c5][s5] = lmax;
        }
        __syncthreads();
        if (tid < 16) {
            float m0 = red[tid][0];
            for (int s = 1; s < 32; ++s) m0 = fmaxf(m0, red[tid][s]);
            m0S[tid] = m0;
            mslot[0][tid] = 1.0f;   // M'_0 = 1 (P0 stored max-normalized)
            mslot[1][tid] = 0.0f;
            mslot[2][tid] = 0.0f;
            mslot[3][tid] = 0.0f;
        }
        __syncthreads();
        // ---- fwd init pass 2: store P0 (max = 1) in permuted layout ----
        {
            float m0 = m0S[c5];
#pragma unroll
            for (int i = 0; i < 4; ++i) {
                int pd = s5 + 32 * i;
                int wvv = pd >> 4, rw = pd & 15;
                float f[4];
#pragma unroll
                for (int nt = 0; nt < 4; ++nt) {
                    int k = 64 * wvv + 16 * nt + rw;
                    f[nt] = __expf(emit[(size_t)(B0 + c5) * CC + k] + tfs[k] - m0);
                }
                int r = 0;
                r = __builtin_amdgcn_cvt_pk_fp8_f32(f[0], f[1], r, false);
                r = __builtin_amdgcn_cvt_pk_fp8_f32(f[2], f[3], r, true);
                *(int*)(&p8[0][0] + c5 * 528 + pd * 4) = r;
            }
        }
        __syncthreads();
    } else {
        // ---- bwd init: mInit = max_k exp(t2e[k]) ----
        {
            float m = t2e[tid];
            for (int off = 32; off > 0; off >>= 1) m = fmaxf(m, __shfl_xor(m, off));
            if (lane == 0) ((float*)red)[wv] = m;
        }
        if (tid < 16) {
            mslot[0][tid] = 0.0f;
            mslot[1][tid] = 0.0f;
            mslot[2][tid] = 0.0f;
            mslot[3][tid] = 0.0f;
        }
        __syncthreads();
        if (tid == 0) {
            float m = ((float*)red)[0];
            for (int i = 1; i < 8; ++i) m = fmaxf(m, ((float*)red)[i]);
            mInitS = __expf(m);
        }
        __syncthreads();
        // ---- bwd init: beta_511 = exp(t2e) in BOTH buffers; chain lengths ----
        {
#pragma unroll
            for (int i = 0; i < 4; ++i) {
                int pd = s5 + 32 * i;
                int wvv = pd >> 4, rw = pd & 15;
                float f[4];
#pragma unroll
                for (int nt = 0; nt < 4; ++nt)
                    f[nt] = __expf(t2e[64 * wvv + 16 * nt + rw]);
                int r = 0;
                r = __builtin_amdgcn_cvt_pk_fp8_f32(f[0], f[1], r, false);
                r = __builtin_amdgcn_cvt_pk_fp8_f32(f[2], f[3], r, true);
                *(int*)(&p8[0][0] + c5 * 528 + pd * 4) = r;
                *(int*)(&p8[1][0] + c5 * 528 + pd * 4) = r;
            }
            int part = 0;
            for (int k = 0; k < 16; ++k)
                part += mask_at(maskp, is_byte, s5 * 16 + k, B0 + c5) ? 1 : 0;
            red[c5][s5] = (float)part;
        }
        __syncthreads();
        if (tid < 16) {
            int s = 0;
            for (int i = 0; i < 32; ++i) s += (int)red[tid][i];
            lenS[tid] = s;
        }
        __syncthreads();
    }

    int4v gsum = {0, 0, 0, 0};
    const float4v z4 = {0.f, 0.f, 0.f, 0.f};
    const float4v c448 = 448.0f;

    if (is_fwd) {
        // =========================== FORWARD: t = 1..255 ===========================
        const float* eb0 = emit + (size_t)(BB + B0 + q * 4) * CC + (wv * 64 + r15);
        const float* eb1 = eb0 + 2 * CC;
        float4v ex4[4];
#pragma unroll
        for (int nt = 0; nt < 4; ++nt) {
            ex4[nt][0] = __expf(eb0[0 * CC + nt * 16]);
            ex4[nt][1] = __expf(eb0[1 * CC + nt * 16]);
            ex4[nt][2] = __expf(eb1[0 * CC + nt * 16]);
            ex4[nt][3] = __expf(eb1[1 * CC + nt * 16]);
        }

#pragma unroll 2
        for (int t = 1; t <= TM; ++t) {
            const int wp = t & 1;
            const int rp = wp ^ 1;
            eb0 += BB * CC;   // now points at t+1 (t=TM reads t=256: valid, unused)
            eb1 += BB * CC;

            const unsigned char* pr = &p8[rp][0] + r15 * 528 + q * 32;
            int8v af[4];
#pragma unroll
            for (int kk4 = 0; kk4 < 4; ++kk4) {
                int4v lo = *(const int4v*)(pr + kk4 * 128);
                int4v hi = *(const int4v*)(pr + kk4 * 128 + 16);
                af[kk4] = __builtin_shufflevector(lo, hi, 0, 1, 2, 3, 4, 5, 6, 7);
            }
            int4v me = *(const int4v*)&mslot[(t - 1) & 3][q * 4];   // f32 bits of M'

            float4v emn4[4];
#pragma unroll
            for (int nt = 0; nt < 4; ++nt) {
                emn4[nt][0] = eb0[0 * CC + nt * 16];
                emn4[nt][1] = eb0[1 * CC + nt * 16];
                emn4[nt][2] = eb1[0 * CC + nt * 16];
                emn4[nt][3] = eb1[1 * CC + nt * 16];
            }

            // s2 = 2^-(e-121), g = e-121  (sigma = 64*pow2floor(M'))
            int4v e4 = me >> 23;
            int4v s2b = (248 - e4) << 23;
            float4v s24;
            s24[0] = __int_as_float(s2b[0]); s24[1] = __int_as_float(s2b[1]);
            s24[2] = __int_as_float(s2b[2]); s24[3] = __int_as_float(s2b[3]);

            if (wv == 0 && r15 == 0)
                *(float4v*)&mslot[(t + 1) & 3][q * 4] = z4;

            float4v acc0 = z4, acc1 = z4, acc2 = z4, acc3 = z4;

            // ---- MFMA pair A: nt 0,1 ----
            __builtin_amdgcn_s_setprio(1);
#pragma unroll
            for (int kk4 = 0; kk4 < 4; ++kk4) {
                acc0 = __builtin_amdgcn_mfma_scale_f32_16x16x128_f8f6f4(
                    af[kk4], ef[0][kk4], acc0, 0, 0, 0, 0x7F7F7F7F, 0, 0x7F7F7F7F);
                acc1 = __builtin_amdgcn_mfma_scale_f32_16x16x128_f8f6f4(
                    af[kk4], ef[1][kk4], acc1, 0, 0, 0, 0x7F7F7F7F, 0, 0x7F7F7F7F);
            }
            __builtin_amdgcn_s_setprio(0);

            // epilogue A (overlaps pair-B execution)
            float4v p0 = acc0 * (ex4[0] * s24);
            float4v p1 = acc1 * (ex4[1] * s24);
            float4v rmA = __builtin_elementwise_max(p0, p1);
#pragma unroll
            for (int rr = 0; rr < 4; ++rr) {
                float mr = rowmax16_dpp(rmA[rr]);
                if (r15 == 0)
                    atomicMax((int*)&mslot[t & 3][q * 4 + rr], __float_as_int(mr));
            }
            float4v pA0 = __builtin_elementwise_min(p0, c448);
            float4v pA1 = __builtin_elementwise_min(p1, c448);
            int rlo[4];
#pragma unroll
            for (int rr = 0; rr < 4; ++rr)
                rlo[rr] = __builtin_amdgcn_cvt_pk_fp8_f32(pA0[rr], pA1[rr], 0, false);

            float4v exn0, exn1;
            exn0[0] = __expf(emn4[0][0]); exn0[1] = __expf(emn4[0][1]);
            exn0[2] = __expf(emn4[0][2]); exn0[3] = __expf(emn4[0][3]);
            exn1[0] = __expf(emn4[1][0]); exn1[1] = __expf(emn4[1][1]);
            exn1[2] = __expf(emn4[1][2]); exn1[3] = __expf(emn4[1][3]);

            // ---- MFMA pair B: nt 2,3 ----
            __builtin_amdgcn_s_setprio(1);
#pragma unroll
            for (int kk4 = 0; kk4 < 4; ++kk4) {
                acc2 = __builtin_amdgcn_mfma_scale_f32_16x16x128_f8f6f4(
                    af[kk4], ef[2][kk4], acc2, 0, 0, 0, 0x7F7F7F7F, 0, 0x7F7F7F7F);
                acc3 = __builtin_amdgcn_mfma_scale_f32_16x16x128_f8f6f4(
                    af[kk4], ef[3][kk4], acc3, 0, 0, 0, 0x7F7F7F7F, 0, 0x7F7F7F7F);
            }
            __builtin_amdgcn_s_setprio(0);

            float4v exn2, exn3;
            exn2[0] = __expf(emn4[2][0]); exn2[1] = __expf(emn4[2][1]);
            exn2[2] = __expf(emn4[2][2]); exn2[3] = __expf(emn4[2][3]);
            exn3[0] = __expf(emn4[3][0]); exn3[1] = __expf(emn4[3][1]);
            exn3[2] = __expf(emn4[3][2]); exn3[3] = __expf(emn4[3][3]);

            // epilogue B
            float4v p2 = acc2 * (ex4[2] * s24);
            float4v p3 = acc3 * (ex4[3] * s24);
            float4v rmB = __builtin_elementwise_max(p2, p3);
#pragma unroll
            for (int rr = 0; rr < 4; ++rr) {
                float mr = rowmax16_dpp(rmB[rr]);
                if (r15 == 0)
                    atomicMax((int*)&mslot[t & 3][q * 4 + rr], __float_as_int(mr));
            }
            float4v pB0 = __builtin_elementwise_min(p2, c448);
            float4v pB1 = __builtin_elementwise_min(p3, c448);
            {
                unsigned char* wrow = &p8[wp][0] + (wv * 16 + r15) * 4;
#pragma unroll
                for (int rr = 0; rr < 4; ++rr) {
                    int r = __builtin_amdgcn_cvt_pk_fp8_f32(pB0[rr], pB1[rr], rlo[rr], true);
                    *(int*)(wrow + (q * 4 + rr) * 528) = r;
                }
            }

            if (t == TM) {   // export stored-scale alpha_255 (f32, class order)
                float* wA = (float*)(ws + WS_ALPHA) + (size_t)(B0 + q * 4) * CC + (wv * 64 + r15);
#pragma unroll
                for (int rr = 0; rr < 4; ++rr) {
                    wA[(size_t)rr * CC +  0] = p0[rr];
                    wA[(size_t)rr * CC + 16] = p1[rr];
                    wA[(size_t)rr * CC + 32] = p2[rr];
                    wA[(size_t)rr * CC + 48] = p3[rr];
                }
            }

            gsum += (e4 - 121);   // fwd: always live (all lanes keep identical copies)

            ex4[0] = exn0; ex4[1] = exn1; ex4[2] = exn2; ex4[3] = exn3;
            step_barrier();
        }
        if (wv == 0 && r15 == 0) {
#pragma unroll
            for (int rr = 0; rr < 4; ++rr)
                ((float*)(ws + WS_SVA))[B0 + q * 4 + rr] =
                    m0S[q * 4 + rr] + 0.6931471805599453f * (float)gsum[rr];
        }
    } else {
        // =========================== BACKWARD: t = 510..255 ===========================
        int lenR[4];
#pragma unroll
        for (int rr = 0; rr < 4; ++rr) lenR[rr] = lenS[q * 4 + rr];
        const int eInit = __float_as_int(mInitS) >> 23;

        // init-int for frozen-row rewrite (branchless store)
        int rInit = 0;
        rInit = __builtin_amdgcn_cvt_pk_fp8_f32(__expf(t2e[64 * wv + r15]),
                                                __expf(t2e[64 * wv + 16 + r15]), rInit, false);
        rInit = __builtin_amdgcn_cvt_pk_fp8_f32(__expf(t2e[64 * wv + 32 + r15]),
                                                __expf(t2e[64 * wv + 48 + r15]), rInit, true);

        const float* eb0 = emit + ((size_t)(LL - 1) * BB + B0 + q * 4) * CC + (wv * 64 + r15);
        const float* eb1 = eb0 + 2 * CC;
        float4v ex4[4];
#pragma unroll
        for (int nt = 0; nt < 4; ++nt) {
            ex4[nt][0] = __expf(eb0[0 * CC + nt * 16]);
            ex4[nt][1] = __expf(eb0[1 * CC + nt * 16]);
            ex4[nt][2] = __expf(eb1[0 * CC + nt * 16]);
            ex4[nt][3] = __expf(eb1[1 * CC + nt * 16]);
        }

#pragma unroll 2
        for (int it = 0; it < 256; ++it) {
            const int t  = 510 - it;
            const int wp = it & 1;
            const int rp = wp ^ 1;
            eb0 -= BB * CC;   // it=255 reads t=254 region: valid, unused
            eb1 -= BB * CC;

            const unsigned char* pr = &p8[rp][0] + r15 * 528 + q * 32;
            int8v af[4];
#pragma unroll
            for (int kk4 = 0; kk4 < 4; ++kk4) {
                int4v lo = *(const int4v*)(pr + kk4 * 128);
                int4v hi = *(const int4v*)(pr + kk4 * 128 + 16);
                af[kk4] = __builtin_shufflevector(lo, hi, 0, 1, 2, 3, 4, 5, 6, 7);
            }
            int4v me = *(const int4v*)&mslot[(it + 3) & 3][q * 4];

            float4v emn4[4];
#pragma unroll
            for (int nt = 0; nt < 4; ++nt) {
                emn4[nt][0] = eb0[0 * CC + nt * 16];
                emn4[nt][1] = eb0[1 * CC + nt * 16];
                emn4[nt][2] = eb1[0 * CC + nt * 16];
                emn4[nt][3] = eb1[1 * CC + nt * 16];
            }

            // per-row g select: frozen-prev rows use eInit (prev row = init, scale 1)
            int4v e4 = me >> 23;
            int4v eU;
            float4v s2U;
            bool live[4];
#pragma unroll
            for (int rr = 0; rr < 4; ++rr) {
                bool ui = (t >= lenR[rr] - 2);
                live[rr] = !ui;
                int e = ui ? eInit : e4[rr];
                eU[rr] = e;
                s2U[rr] = __int_as_float((248 - e) << 23);
            }

            if (wv == 0 && r15 == 0)
                *(float4v*)&mslot[(it + 1) & 3][q * 4] = z4;

            float4v acc0 = z4, acc1 = z4, acc2 = z4, acc3 = z4;

            // ---- MFMA pair A: nt 0,1 ----
            __builtin_amdgcn_s_setprio(1);
#pragma unroll
            for (int kk4 = 0; kk4 < 4; ++kk4) {
                acc0 = __builtin_amdgcn_mfma_scale_f32_16x16x128_f8f6f4(
                    af[kk4], ef[0][kk4], acc0, 0, 0, 0, 0x7F7F7F7F, 0, 0x7F7F7F7F);
                acc1 = __builtin_amdgcn_mfma_scale_f32_16x16x128_f8f6f4(
                    af[kk4], ef[1][kk4], acc1, 0, 0, 0, 0x7F7F7F7F, 0, 0x7F7F7F7F);
            }
            __builtin_amdgcn_s_setprio(0);

            float4v p0 = acc0 * (ex4[0] * s2U);
            float4v p1 = acc1 * (ex4[1] * s2U);
            float4v rmA = __builtin_elementwise_max(p0, p1);
#pragma unroll
            for (int rr = 0; rr < 4; ++rr) {
                float mr = rowmax16_dpp(rmA[rr]);
                if (r15 == 0)
                    atomicMax((int*)&mslot[it & 3][q * 4 + rr], __float_as_int(mr));
            }
            float4v pA0 = __builtin_elementwise_min(p0, c448);
            float4v pA1 = __builtin_elementwise_min(p1, c448);
            int rlo[4];
#pragma unroll
            for (int rr = 0; rr < 4; ++rr)
                rlo[rr] = __builtin_amdgcn_cvt_pk_fp8_f32(pA0[rr], pA1[rr], 0, false);

            float4v exn0, exn1;
            exn0[0] = __expf(emn4[0][0]); exn0[1] = __expf(emn4[0][1]);
            exn0[2] = __expf(emn4[0][2]); exn0[3] = __expf(emn4[0][3]);
            exn1[0] = __expf(emn4[1][0]); exn1[1] = __expf(emn4[1][1]);
            exn1[2] = __expf(emn4[1][2]); exn1[3] = __expf(emn4[1][3]);

            // ---- MFMA pair B: nt 2,3 ----
            __builtin_amdgcn_s_setprio(1);
#pragma unroll
            for (int kk4 = 0; kk4 < 4; ++kk4) {
                acc2 = __builtin_amdgcn_mfma_scale_f32_16x16x128_f8f6f4(
                    af[kk4], ef[2][kk4], acc2, 0, 0, 0, 0x7F7F7F7F, 0, 0x7F7F7F7F);
                acc3 = __builtin_amdgcn_mfma_scale_f32_16x16x128_f8f6f4(
                    af[kk4], ef[3][kk4], acc3, 0, 0, 0, 0x7F7F7F7F, 0, 0x7F7F7F7F);
            }
            __builtin_amdgcn_s_setprio(0);

            float4v exn2, exn3;
            exn2[0] = __expf(emn4[2][0]); exn2[1] = __expf(emn4[2][1]);
            exn2[2] = __expf(emn4[2][2]); exn2[3] = __expf(emn4[2][3]);
            exn3[0] = __expf(emn4[3][0]); exn3[1] = __expf(emn4[3][1]);
            exn3[2] = __expf(emn4[3][2]); exn3[3] = __expf(emn4[3][3]);

            float4v p2 = acc2 * (ex4[2] * s2U);
            float4v p3 = acc3 * (ex4[3] * s2U);
            float4v rmB = __builtin_elementwise_max(p2, p3);
#pragma unroll
            for (int rr = 0; rr < 4; ++rr) {
                float mr = rowmax16_dpp(rmB[rr]);
                if (r15 == 0)
                    atomicMax((int*)&mslot[it & 3][q * 4 + rr], __float_as_int(mr));
            }
            float4v pB0 = __builtin_elementwise_min(p2, c448);
            float4v pB1 = __builtin_elementwise_min(p3, c448);
            {
                unsigned char* wrow = &p8[wp][0] + (wv * 16 + r15) * 4;
#pragma unroll
                for (int rr = 0; rr < 4; ++rr) {
                    int r = __builtin_amdgcn_cvt_pk_fp8_f32(pB0[rr], pB1[rr], rlo[rr], true);
                    int rs = live[rr] ? r : rInit;   // frozen rows rewrite init (branchless)
                    *(int*)(wrow + (q * 4 + rr) * 528) = rs;
                }
            }

            if (t == TM) {   // export stored-scale beta_255 (frozen chains: e^{t2e} row)
                float* wB = (float*)(ws + WS_BETA) + (size_t)(B0 + q * 4) * CC + (wv * 64 + r15);
#pragma unroll
                for (int nt = 0; nt < 4; ++nt) {
                    float e2 = __expf(t2e[wv * 64 + nt * 16 + r15]);
                    float4v* psel = (nt == 0) ? &p0 : (nt == 1) ? &p1 : (nt == 2) ? &p2 : &p3;
#pragma unroll
                    for (int rr = 0; rr < 4; ++rr)
                        wB[(size_t)rr * CC + nt * 16] = live[rr] ? (*psel)[rr] : e2;
                }
            }

#pragma unroll
            for (int rr = 0; rr < 4; ++rr)
                gsum[rr] += live[rr] ? (eU[rr] - 121) : 0;

            ex4[0] = exn0; ex4[1] = exn1; ex4[2] = exn2; ex4[3] = exn3;
            step_barrier();
        }
        if (wv == 0 && r15 == 0) {
#pragma unroll
            for (int rr = 0; rr < 4; ++rr)
                ((float*)(ws + WS_SVB))[B0 + q * 4 + rr] =
                    0.6931471805599453f * (float)gsum[rr];
        }
    }
}

// ---------------- combine: logZ_b = SvA_b + SvB_b + log(alpha_255 . beta_255) -----------
__global__ void combine_kernel(const unsigned char* __restrict__ ws, float* __restrict__ out) {
    __shared__ float acc8[8];
    const int tid = threadIdx.x;
    const int c  = tid >> 3;
    const int s8 = tid & 7;
    const float* A = (const float*)(ws + WS_ALPHA) + (size_t)c * CC;
    const float* B = (const float*)(ws + WS_BETA)  + (size_t)c * CC;
    float d = 0.0f;
    for (int i = s8; i < CC; i += 8) d += A[i] * B[i];
    d += __shfl_xor(d, 1);
    d += __shfl_xor(d, 2);
    d += __shfl_xor(d, 4);
    float v = 0.0f;
    if (s8 == 0)
        v = ((const float*)(ws + WS_SVA))[c] + ((const float*)(ws + WS_SVB))[c] + __logf(d);
    for (int off = 32; off > 0; off >>= 1) v += __shfl_down(v, off);
    if ((tid & 63) == 0) acc8[tid >> 6] = v;
    __syncthreads();
    if (tid == 0) {
        float s = 0.0f;
        for (int i = 0; i < 8; ++i) s += acc8[i];
        float sc = 0.0f;
        for (int i = 0; i < 32; ++i) sc += ((const float*)(ws + WS_SPART))[i];
        out[0] = (s - sc) * (1.0f / 64.0f);
    }
}

extern "C" void kernel_launch(void* const* d_in, const int* in_sizes, int n_in,
                              void* d_out, int out_size, void* d_ws, size_t ws_size,
                              hipStream_t stream) {
    const float* emit   = (const float*)d_in[0];
    const int*   target = (const int*)d_in[1];
    const void*  maskp  = d_in[2];
    const float* trans  = (const float*)d_in[3];
    const float* tfs    = (const float*)d_in[4];
    const float* t2e    = (const float*)d_in[5];
    unsigned char* ws   = (unsigned char*)d_ws;
    float* out          = (float*)d_out;

    crf_scan_kernel<<<40, 512, 0, stream>>>(emit, target, maskp, trans, tfs, t2e, ws);
    combine_kernel<<<1, 512, 0, stream>>>(ws, out);
}

// Round 5
// 492.456 us; speedup vs baseline: 1.4499x; 1.4499x over previous
//
#include <hip/hip_runtime.h>
#include <hip/hip_bf16.h>
#include <stdint.h>

#define LL 512
#define BB 64
#define CC 512
#define TM 255   // meeting point: fwd covers emits 0..255, bwd covers 256..511

typedef float float4v __attribute__((ext_vector_type(4)));
typedef int   int4v   __attribute__((ext_vector_type(4)));
typedef unsigned int uint4v __attribute__((ext_vector_type(4)));
typedef int   int8v  __attribute__((ext_vector_type(8)));

// ws layout (bytes)
#define WS_ET     262144   // E^T fp8 (E fwd fp8 at 0)
#define WS_SCORE  524288   // f32
#define WS_SVA    524292   // 64 f32
#define WS_SVB    524548   // 64 f32
#define WS_ALPHA  528384   // 64*512 f32 (class-ordered)
#define WS_BETA   659456   // 64*512 f32 (class-ordered)

// position permutation shared by p8 rows and E/E^T columns:
//   kperm(P) = 64*(P>>6) + 16*(P&3) + ((P>>2)&15)
//
// normalization (pow2): stored S_t = quant(v_t * 2^-g_t), v_t = MFMA(S_{t-1})*ex_t,
//   g_t = floor(log2(M'_{t-1})) + 6,  M'_{t-1} = max(stored S_{t-1})
//   M' tracking is ATOMIC-FREE: each wave writes its 16 row-maxes to
//   mslotW[t&1][wv][chain]; the consumer (next step) u32-maxes the 8 wave slots.
//   true alpha_t = S_t * D_t, logD = gsum * ln2  (exact)

__device__ __forceinline__ bool mask_at(const void* maskp, bool is_byte, int t, int b) {
    if (is_byte) return ((const unsigned char*)maskp)[t * BB + b] != 0;
    return ((const int*)maskp)[t * BB + b] != 0;
}

__device__ __forceinline__ float rowmax16_dpp(float x) {
    int t;
    t = __builtin_amdgcn_update_dpp(0, __float_as_int(x), 0x128, 0xF, 0xF, true); // ror:8
    x = fmaxf(x, __int_as_float(t));
    t = __builtin_amdgcn_update_dpp(0, __float_as_int(x), 0x124, 0xF, 0xF, true); // ror:4
    x = fmaxf(x, __int_as_float(t));
    t = __builtin_amdgcn_update_dpp(0, __float_as_int(x), 0x122, 0xF, 0xF, true); // ror:2
    x = fmaxf(x, __int_as_float(t));
    t = __builtin_amdgcn_update_dpp(0, __float_as_int(x), 0x121, 0xF, 0xF, true); // ror:1
    x = fmaxf(x, __int_as_float(t));
    return x;
}

// LDS-exchange barrier WITHOUT vmcnt drain: global prefetches stay in flight.
__device__ __forceinline__ void step_barrier() {
    asm volatile("s_waitcnt lgkmcnt(0)" ::: "memory");
    __builtin_amdgcn_sched_barrier(0);
    __builtin_amdgcn_s_barrier();
    asm volatile("" ::: "memory");
}

// E (fwd) and E^T (bwd) in fp8, permuted layout. Also zero the score slot.
__global__ void prep_kernel(const float* __restrict__ trans, unsigned char* __restrict__ ws) {
    int g = blockIdx.x * blockDim.x + threadIdx.x;
    if (g == 0) *(float*)(ws + WS_SCORE) = 0.0f;
    if (g >= 512 * 128) return;
    int n  = g & 511;
    int pd = g >> 9;
    int wv = pd >> 4, rw = pd & 15;
    float f[4], ft[4];
#pragma unroll
    for (int nt = 0; nt < 4; ++nt) {
        int k = 64 * wv + 16 * nt + rw;
        f[nt]  = __expf(trans[(size_t)k * CC + n]);   // E[k][n]
        ft[nt] = __expf(trans[(size_t)n * CC + k]);   // E[n][k]
    }
    int r = 0;
    r = __builtin_amdgcn_cvt_pk_fp8_f32(f[0], f[1], r, false);
    r = __builtin_amdgcn_cvt_pk_fp8_f32(f[2], f[3], r, true);
    ((int*)ws)[n * 128 + pd] = r;
    int r2 = 0;
    r2 = __builtin_amdgcn_cvt_pk_fp8_f32(ft[0], ft[1], r2, false);
    r2 = __builtin_amdgcn_cvt_pk_fp8_f32(ft[2], ft[3], r2, true);
    ((int*)(ws + WS_ET))[n * 128 + pd] = r2;
}

// blocks 0..3: fwd alpha t=1..255 (len>=256 -> unguarded)
// blocks 4..7: bwd beta t=510..255 (freeze-until-birth)
// blocks 8..39: score
__launch_bounds__(512, 2)
__global__ void crf_scan_kernel(const float* __restrict__ emit,
                                const int* __restrict__ target,
                                const void* __restrict__ maskp,
                                const float* __restrict__ trans,
                                const float* __restrict__ tfs,
                                const float* __restrict__ t2e,
                                unsigned char* __restrict__ ws) {
    const int tid = threadIdx.x;
    const bool is_byte = ((const unsigned char*)maskp)[1] != 0;

    if (blockIdx.x >= 8) {   // -------- score part --------
        int sb = blockIdx.x - 8;
        float val = 0.0f;
        for (int e = sb * 512 + tid; e < LL * BB; e += 32 * 512) {
            int t = e >> 6, b = e & 63;
            if (mask_at(maskp, is_byte, t, b)) {
                int tg  = target[t * BB + b];
                float v = emit[(size_t)(t * BB + b) * CC + tg];
                if (t > 0) v += trans[(size_t)target[(t - 1) * BB + b] * CC + tg];
                val += v;
            }
        }
        if (sb == 0 && tid < BB) {
            int b = tid;
            val += tfs[target[b]];
            int lo = 0, hi = LL;
            while (lo < hi) {
                int mid = (lo + hi) >> 1;
                if (mask_at(maskp, is_byte, mid, b)) lo = mid + 1; else hi = mid;
            }
            val += t2e[target[(lo - 1) * BB + b]];
        }
        for (int off = 32; off > 0; off >>= 1) val += __shfl_down(val, off);
        if ((tid & 63) == 0) atomicAdd((float*)(ws + WS_SCORE), val);
        return;
    }

    const bool is_fwd = blockIdx.x < 4;
    const int B0 = (is_fwd ? blockIdx.x : blockIdx.x - 4) * 16;

    __shared__ __align__(16) unsigned char p8[2][16 * 528];
    __shared__ __align__(16) float mslotW[2][8][16];   // per-wave rowmax slots, ring 2
    __shared__ float m0S[16];
    __shared__ float red[16][32];
    __shared__ int   lenS[16];
    __shared__ float mInitS;

    const int wv   = tid >> 6;
    const int lane = tid & 63;
    const int q    = lane >> 4;
    const int r15  = lane & 15;

    // E (B operand) fragments resident in VGPRs (AGPR-backed)
    const unsigned char* ews = ws + (is_fwd ? 0 : WS_ET);
    int8v ef[4][4];
#pragma unroll
    for (int nt = 0; nt < 4; ++nt) {
        int n = (wv * 4 + nt) * 16 + r15;
#pragma unroll
        for (int kk4 = 0; kk4 < 4; ++kk4) {
            const unsigned char* src = ews + n * 512 + kk4 * 128 + q * 32;
            int4v lo = *(const int4v*)(src);
            int4v hi = *(const int4v*)(src + 16);
            ef[nt][kk4] = __builtin_shufflevector(lo, hi, 0, 1, 2, 3, 4, 5, 6, 7);
        }
    }

    const int c5 = tid >> 5;
    const int s5 = tid & 31;

    if (is_fwd) {
        // ---- fwd init pass 1: m0 = max(emit[0]+tfs) per chain ----
        {
            float lmax = -3.0e38f;
#pragma unroll
            for (int i = 0; i < 4; ++i) {
                int j4 = s5 + 32 * i;
                float4v em = *(const float4v*)(emit + (size_t)(B0 + c5) * CC + 4 * j4);
                float4v tf = *(const float4v*)(tfs + 4 * j4);
                float4v a = em + tf;
                lmax = fmaxf(lmax, fmaxf(fmaxf(a.x, a.y), fmaxf(a.z, a.w)));
            }
            red[c5][s5] = lmax;
        }
        __syncthreads();
        if (tid < 16) {
            float m0 = red[tid][0];
            for (int s = 1; s < 32; ++s) m0 = fmaxf(m0, red[tid][s]);
            m0S[tid] = m0;
        }
        if (tid < 128) ((float*)&mslotW[0][0][0])[tid] = 1.0f;   // M'_0 = 1, all wave slots
        __syncthreads();
        // ---- fwd init pass 2: store P0 (max = 1) in permuted layout ----
        {
            float m0 = m0S[c5];
#pragma unroll
            for (int i = 0; i < 4; ++i) {
                int pd = s5 + 32 * i;
                int wvv = pd >> 4, rw = pd & 15;
                float f[4];
#pragma unroll
                for (int nt = 0; nt < 4; ++nt) {
                    int k = 64 * wvv + 16 * nt + rw;
                    f[nt] = __expf(emit[(size_t)(B0 + c5) * CC + k] + tfs[k] - m0);
                }
                int r = 0;
                r = __builtin_amdgcn_cvt_pk_fp8_f32(f[0], f[1], r, false);
                r = __builtin_amdgcn_cvt_pk_fp8_f32(f[2], f[3], r, true);
                *(int*)(&p8[0][0] + c5 * 528 + pd * 4) = r;
            }
        }
        __syncthreads();
    } else {
        // ---- bwd init: mInit = max_k exp(t2e[k]) ----
        {
            float m = t2e[tid];
            for (int off = 32; off > 0; off >>= 1) m = fmaxf(m, __shfl_xor(m, off));
            if (lane == 0) ((float*)red)[wv] = m;
        }
        __syncthreads();
        if (tid == 0) {
            float m = ((float*)red)[0];
            for (int i = 1; i < 8; ++i) m = fmaxf(m, ((float*)red)[i]);
            mInitS = __expf(m);
        }
        __syncthreads();
        // ---- bwd init: beta_511 = exp(t2e) in BOTH buffers; chain lengths ----
        {
#pragma unroll
            for (int i = 0; i < 4; ++i) {
                int pd = s5 + 32 * i;
                int wvv = pd >> 4, rw = pd & 15;
                float f[4];
#pragma unroll
                for (int nt = 0; nt < 4; ++nt)
                    f[nt] = __expf(t2e[64 * wvv + 16 * nt + rw]);
                int r = 0;
                r = __builtin_amdgcn_cvt_pk_fp8_f32(f[0], f[1], r, false);
                r = __builtin_amdgcn_cvt_pk_fp8_f32(f[2], f[3], r, true);
                *(int*)(&p8[0][0] + c5 * 528 + pd * 4) = r;
                *(int*)(&p8[1][0] + c5 * 528 + pd * 4) = r;
            }
            int part = 0;
            for (int k = 0; k < 16; ++k)
                part += mask_at(maskp, is_byte, s5 * 16 + k, B0 + c5) ? 1 : 0;
            red[c5][s5] = (float)part;
        }
        __syncthreads();
        if (tid < 16) {
            int s = 0;
            for (int i = 0; i < 32; ++i) s += (int)red[tid][i];
            lenS[tid] = s;
        }
        __syncthreads();
    }

    int4v gsum = {0, 0, 0, 0};
    const float4v z4 = {0.f, 0.f, 0.f, 0.f};

    if (is_fwd) {
        // =========================== FORWARD: t = 1..255 ===========================
        const float* eb0 = emit + (size_t)(BB + B0 + q * 4) * CC + (wv * 64 + r15);
        const float* eb1 = eb0 + 2 * CC;
        float4v ex4[4];
#pragma unroll
        for (int nt = 0; nt < 4; ++nt) {
            ex4[nt][0] = __expf(eb0[0 * CC + nt * 16]);
            ex4[nt][1] = __expf(eb0[1 * CC + nt * 16]);
            ex4[nt][2] = __expf(eb1[0 * CC + nt * 16]);
            ex4[nt][3] = __expf(eb1[1 * CC + nt * 16]);
        }

#pragma unroll 2
        for (int t = 1; t <= TM; ++t) {
            const int wp = t & 1;
            const int rp = wp ^ 1;
            eb0 += BB * CC;   // now points at t+1 (t=TM reads t=256: valid, unused)
            eb1 += BB * CC;

            const unsigned char* pr = &p8[rp][0] + r15 * 528 + q * 32;
            int8v af[4];
#pragma unroll
            for (int kk4 = 0; kk4 < 4; ++kk4) {
                int4v lo = *(const int4v*)(pr + kk4 * 128);
                int4v hi = *(const int4v*)(pr + kk4 * 128 + 16);
                af[kk4] = __builtin_shufflevector(lo, hi, 0, 1, 2, 3, 4, 5, 6, 7);
            }

            // consumer-side max over the 8 wave slots (u32 max == f32 max for positives)
            const char* mb = (const char*)&mslotW[(t - 1) & 1][0][q * 4];
            uint4v mm = *(const uint4v*)(mb);
#pragma unroll
            for (int i = 1; i < 8; ++i)
                mm = __builtin_elementwise_max(mm, *(const uint4v*)(mb + i * 64));

            float4v emn4[4];
#pragma unroll
            for (int nt = 0; nt < 4; ++nt) {
                emn4[nt][0] = eb0[0 * CC + nt * 16];
                emn4[nt][1] = eb0[1 * CC + nt * 16];
                emn4[nt][2] = eb1[0 * CC + nt * 16];
                emn4[nt][3] = eb1[1 * CC + nt * 16];
            }

            // s2 = 2^-(e-121), g = e-121  (sigma = 64*pow2floor(M'))
            int4v e4 = {(int)(mm[0] >> 23), (int)(mm[1] >> 23), (int)(mm[2] >> 23), (int)(mm[3] >> 23)};
            int4v s2b = (248 - e4) << 23;
            float4v s24;
            s24[0] = __int_as_float(s2b[0]); s24[1] = __int_as_float(s2b[1]);
            s24[2] = __int_as_float(s2b[2]); s24[3] = __int_as_float(s2b[3]);

            float4v acc[4];
#pragma unroll
            for (int nt = 0; nt < 4; ++nt) acc[nt] = z4;

#pragma unroll
            for (int kk4 = 0; kk4 < 4; ++kk4)
#pragma unroll
                for (int nt = 0; nt < 2; ++nt)
                    acc[nt] = __builtin_amdgcn_mfma_scale_f32_16x16x128_f8f6f4(
                        af[kk4], ef[nt][kk4], acc[nt],
                        0, 0, 0, 0x7F7F7F7F, 0, 0x7F7F7F7F);

            float4v exn4[4];
#pragma unroll
            for (int nt = 0; nt < 4; ++nt) {
                exn4[nt][0] = __expf(emn4[nt][0]);
                exn4[nt][1] = __expf(emn4[nt][1]);
                exn4[nt][2] = __expf(emn4[nt][2]);
                exn4[nt][3] = __expf(emn4[nt][3]);
            }

#pragma unroll
            for (int kk4 = 0; kk4 < 4; ++kk4)
#pragma unroll
                for (int nt = 2; nt < 4; ++nt)
                    acc[nt] = __builtin_amdgcn_mfma_scale_f32_16x16x128_f8f6f4(
                        af[kk4], ef[nt][kk4], acc[nt],
                        0, 0, 0, 0x7F7F7F7F, 0, 0x7F7F7F7F);

            // p = acc * (ex * 2^-g)   (stored-scale output)
            float4v p4[4];
#pragma unroll
            for (int nt = 0; nt < 4; ++nt) {
                float4v exr = ex4[nt] * s24;
                p4[nt] = acc[nt] * exr;
            }

            if (t == TM) {   // export stored-scale alpha_255 (f32, class order)
                float* wA = (float*)(ws + WS_ALPHA) + (size_t)(B0 + q * 4) * CC + (wv * 64 + r15);
#pragma unroll
                for (int nt = 0; nt < 4; ++nt)
#pragma unroll
                    for (int rr = 0; rr < 4; ++rr)
                        wA[(size_t)rr * CC + nt * 16] = p4[nt][rr];
            }

            // rowmax (stored scale) -> DPP -> plain per-wave slot write (no atomics)
            {
                float4v rm4 = __builtin_elementwise_max(
                    __builtin_elementwise_max(p4[0], p4[1]),
                    __builtin_elementwise_max(p4[2], p4[3]));
                float4v rw;
#pragma unroll
                for (int rr = 0; rr < 4; ++rr) rw[rr] = rowmax16_dpp(rm4[rr]);
                if (r15 == 0)
                    *(float4v*)&mslotW[t & 1][wv][q * 4] = rw;
            }

            // quantize + store
            {
                unsigned char* wrow = &p8[wp][0] + (wv * 16 + r15) * 4;
#pragma unroll
                for (int rr = 0; rr < 4; ++rr) {
                    float p0 = fminf(p4[0][rr], 448.0f);
                    float p1 = fminf(p4[1][rr], 448.0f);
                    float p2 = fminf(p4[2][rr], 448.0f);
                    float p3 = fminf(p4[3][rr], 448.0f);
                    int r = 0;
                    r = __builtin_amdgcn_cvt_pk_fp8_f32(p0, p1, r, false);
                    r = __builtin_amdgcn_cvt_pk_fp8_f32(p2, p3, r, true);
                    *(int*)(wrow + (q * 4 + rr) * 528) = r;
                }
            }

            if (wv == 0 && r15 == 0) gsum += (e4 - 121);   // fwd: always live

#pragma unroll
            for (int nt = 0; nt < 4; ++nt) ex4[nt] = exn4[nt];
            step_barrier();
        }
        if (wv == 0 && r15 == 0) {
#pragma unroll
            for (int rr = 0; rr < 4; ++rr)
                ((float*)(ws + WS_SVA))[B0 + q * 4 + rr] =
                    m0S[q * 4 + rr] + 0.6931471805599453f * (float)gsum[rr];
        }
    } else {
        // =========================== BACKWARD: t = 510..255 ===========================
        int lenR[4];
#pragma unroll
        for (int rr = 0; rr < 4; ++rr) lenR[rr] = lenS[q * 4 + rr];
        const int eInit = __float_as_int(mInitS) >> 23;

        const float* eb0 = emit + ((size_t)(LL - 1) * BB + B0 + q * 4) * CC + (wv * 64 + r15);
        const float* eb1 = eb0 + 2 * CC;
        float4v ex4[4];
#pragma unroll
        for (int nt = 0; nt < 4; ++nt) {
            ex4[nt][0] = __expf(eb0[0 * CC + nt * 16]);
            ex4[nt][1] = __expf(eb0[1 * CC + nt * 16]);
            ex4[nt][2] = __expf(eb1[0 * CC + nt * 16]);
            ex4[nt][3] = __expf(eb1[1 * CC + nt * 16]);
        }

#pragma unroll 2
        for (int it = 0; it < 256; ++it) {
            const int t  = 510 - it;
            const int wp = it & 1;
            const int rp = wp ^ 1;
            eb0 -= BB * CC;   // it=255 reads t=254 region: valid, unused
            eb1 -= BB * CC;

            const unsigned char* pr = &p8[rp][0] + r15 * 528 + q * 32;
            int8v af[4];
#pragma unroll
            for (int kk4 = 0; kk4 < 4; ++kk4) {
                int4v lo = *(const int4v*)(pr + kk4 * 128);
                int4v hi = *(const int4v*)(pr + kk4 * 128 + 16);
                af[kk4] = __builtin_shufflevector(lo, hi, 0, 1, 2, 3, 4, 5, 6, 7);
            }

            const char* mb = (const char*)&mslotW[(it - 1) & 1][0][q * 4];
            uint4v mm = *(const uint4v*)(mb);
#pragma unroll
            for (int i = 1; i < 8; ++i)
                mm = __builtin_elementwise_max(mm, *(const uint4v*)(mb + i * 64));

            float4v emn4[4];
#pragma unroll
            for (int nt = 0; nt < 4; ++nt) {
                emn4[nt][0] = eb0[0 * CC + nt * 16];
                emn4[nt][1] = eb0[1 * CC + nt * 16];
                emn4[nt][2] = eb1[0 * CC + nt * 16];
                emn4[nt][3] = eb1[1 * CC + nt * 16];
            }

            // per-row g select: frozen-prev rows (t >= len-2) use eInit (prev = init, scale 1)
            int4v e4 = {(int)(mm[0] >> 23), (int)(mm[1] >> 23), (int)(mm[2] >> 23), (int)(mm[3] >> 23)};
            int4v eU;
            float4v s2U;
#pragma unroll
            for (int rr = 0; rr < 4; ++rr) {
                bool ui = (t >= lenR[rr] - 2);
                int e = ui ? eInit : e4[rr];
                eU[rr] = e;
                s2U[rr] = __int_as_float((248 - e) << 23);
            }

            float4v acc[4];
#pragma unroll
            for (int nt = 0; nt < 4; ++nt) acc[nt] = z4;

#pragma unroll
            for (int kk4 = 0; kk4 < 4; ++kk4)
#pragma unroll
                for (int nt = 0; nt < 2; ++nt)
                    acc[nt] = __builtin_amdgcn_mfma_scale_f32_16x16x128_f8f6f4(
                        af[kk4], ef[nt][kk4], acc[nt],
                        0, 0, 0, 0x7F7F7F7F, 0, 0x7F7F7F7F);

            float4v exn4[4];
#pragma unroll
            for (int nt = 0; nt < 4; ++nt) {
                exn4[nt][0] = __expf(emn4[nt][0]);
                exn4[nt][1] = __expf(emn4[nt][1]);
                exn4[nt][2] = __expf(emn4[nt][2]);
                exn4[nt][3] = __expf(emn4[nt][3]);
            }

#pragma unroll
            for (int kk4 = 0; kk4 < 4; ++kk4)
#pragma unroll
                for (int nt = 2; nt < 4; ++nt)
                    acc[nt] = __builtin_amdgcn_mfma_scale_f32_16x16x128_f8f6f4(
                        af[kk4], ef[nt][kk4], acc[nt],
                        0, 0, 0, 0x7F7F7F7F, 0, 0x7F7F7F7F);

            float4v p4[4];
#pragma unroll
            for (int nt = 0; nt < 4; ++nt) {
                float4v exr = ex4[nt] * s2U;
                p4[nt] = acc[nt] * exr;
            }

            if (t == TM) {   // export stored-scale beta_255 (frozen chains: e^{t2e} row)
                float* wB = (float*)(ws + WS_BETA) + (size_t)(B0 + q * 4) * CC + (wv * 64 + r15);
#pragma unroll
                for (int nt = 0; nt < 4; ++nt) {
                    float e2 = __expf(t2e[wv * 64 + nt * 16 + r15]);
#pragma unroll
                    for (int rr = 0; rr < 4; ++rr)
                        wB[(size_t)rr * CC + nt * 16] = (t <= lenR[rr] - 2) ? p4[nt][rr] : e2;
                }
            }

            {
                float4v rm4 = __builtin_elementwise_max(
                    __builtin_elementwise_max(p4[0], p4[1]),
                    __builtin_elementwise_max(p4[2], p4[3]));
                float4v rw;
#pragma unroll
                for (int rr = 0; rr < 4; ++rr) rw[rr] = rowmax16_dpp(rm4[rr]);
                if (r15 == 0)
                    *(float4v*)&mslotW[it & 1][wv][q * 4] = rw;
            }

            {
                unsigned char* wrow = &p8[wp][0] + (wv * 16 + r15) * 4;
#pragma unroll
                for (int rr = 0; rr < 4; ++rr) {
                    float p0 = fminf(p4[0][rr], 448.0f);
                    float p1 = fminf(p4[1][rr], 448.0f);
                    float p2 = fminf(p4[2][rr], 448.0f);
                    float p3 = fminf(p4[3][rr], 448.0f);
                    int r = 0;
                    r = __builtin_amdgcn_cvt_pk_fp8_f32(p0, p1, r, false);
                    r = __builtin_amdgcn_cvt_pk_fp8_f32(p2, p3, r, true);
                    if (t <= lenR[rr] - 2)   // live update only; frozen rows keep init
                        *(int*)(wrow + (q * 4 + rr) * 528) = r;
                }
            }

            if (wv == 0 && r15 == 0) {
#pragma unroll
                for (int rr = 0; rr < 4; ++rr)
                    if (t <= lenR[rr] - 2) gsum[rr] += (eU[rr] - 121);
            }

#pragma unroll
            for (int nt = 0; nt < 4; ++nt) ex4[nt] = exn4[nt];
            step_barrier();
        }
        if (wv == 0 && r15 == 0) {
#pragma unroll
            for (int rr = 0; rr < 4; ++rr)
                ((float*)(ws + WS_SVB))[B0 + q * 4 + rr] =
                    0.6931471805599453f * (float)gsum[rr];
        }
    }
}

// ---------------- combine: logZ_b = SvA_b + SvB_b + log(alpha_255 . beta_255) -----------
__global__ void combine_kernel(const unsigned char* __restrict__ ws, float* __restrict__ out) {
    __shared__ float acc8[8];
    const int tid = threadIdx.x;
    const int c  = tid >> 3;
    const int s8 = tid & 7;
    const float* A = (const float*)(ws + WS_ALPHA) + (size_t)c * CC;
    const float* B = (const float*)(ws + WS_BETA)  + (size_t)c * CC;
    float d = 0.0f;
    for (int i = s8; i < CC; i += 8) d += A[i] * B[i];
    d += __shfl_xor(d, 1);
    d += __shfl_xor(d, 2);
    d += __shfl_xor(d, 4);
    float v = 0.0f;
    if (s8 == 0)
        v = ((const float*)(ws + WS_SVA))[c] + ((const float*)(ws + WS_SVB))[c] + __logf(d);
    for (int off = 32; off > 0; off >>= 1) v += __shfl_down(v, off);
    if ((tid & 63) == 0) acc8[tid >> 6] = v;
    __syncthreads();
    if (tid == 0) {
        float s = 0.0f;
        for (int i = 0; i < 8; ++i) s += acc8[i];
        out[0] = (s - *(const float*)(ws + WS_SCORE)) * (1.0f / 64.0f);
    }
}

extern "C" void kernel_launch(void* const* d_in, const int* in_sizes, int n_in,
                              void* d_out, int out_size, void* d_ws, size_t ws_size,
                              hipStream_t stream) {
    const float* emit   = (const float*)d_in[0];
    const int*   target = (const int*)d_in[1];
    const void*  maskp  = d_in[2];
    const float* trans  = (const float*)d_in[3];
    const float* tfs    = (const float*)d_in[4];
    const float* t2e    = (const float*)d_in[5];
    unsigned char* ws   = (unsigned char*)d_ws;
    float* out          = (float*)d_out;

    prep_kernel<<<256, 256, 0, stream>>>(trans, ws);
    crf_scan_kernel<<<40, 512, 0, stream>>>(emit, target, maskp, trans, tfs, t2e, ws);
    combine_kernel<<<1, 512, 0, stream>>>(ws, out);
}